// Round 1
// baseline (61.971 us; speedup 1.0000x reference)
//
#include <hip/hip_runtime.h>
#include <math.h>

#define NF 26
#define PF 40000
#define D 16
#define VD (NF * PF * D)   // elements per field table = 16,640,000
#define LIN 13
#define NPAIRS 325         // 26*25/2
#define MAXN 0.01f

__global__ __launch_bounds__(256) void ffm_kernel(
    const float* __restrict__ dense,     // [B, LIN]
    const int*   __restrict__ sparse,    // [B, NF]
    const float* __restrict__ tables,    // [NF, V, D]
    const float* __restrict__ w_sparse,  // [V]
    const float* __restrict__ w_dense,   // [LIN]
    const float* __restrict__ b_dense,   // [1]
    float* __restrict__ out)             // [B]
{
    const int b = blockIdx.x;
    const int t = threadIdx.x;

    __shared__ int   s_idx[NF];
    __shared__ float s_wsum[4];

    if (t < NF) s_idx[t] = sparse[b * NF + t] + t * PF;
    __syncthreads();

    const int g4 = t >> 2;   // pair-group id within block, 0..63
    const int l4 = t & 3;    // lane within group

    float acc = 0.f;
    int i = 0;  // monotone row pointer for pair decode
    for (int p = g4; p < NPAIRS; p += 64) {
        // advance i so that cum(i) <= p < cum(i+1), cum(i) = i*(51-i)/2
        while ((((i + 1) * (51 - (i + 1))) >> 1) <= p) ++i;
        const int j = i + 1 + p - ((i * (51 - i)) >> 1);

        const int ra = s_idx[j];  // row in table i
        const int rb = s_idx[i];  // row in table j

        const float4 a = *reinterpret_cast<const float4*>(
            tables + (size_t)i * VD + (size_t)ra * D + 4 * l4);
        const float4 c = *reinterpret_cast<const float4*>(
            tables + (size_t)j * VD + (size_t)rb * D + 4 * l4);

        float sqa = a.x * a.x + a.y * a.y + a.z * a.z + a.w * a.w;
        float sqc = c.x * c.x + c.y * c.y + c.z * c.z + c.w * c.w;
        sqa += __shfl_xor(sqa, 1, 4); sqa += __shfl_xor(sqa, 2, 4);
        sqc += __shfl_xor(sqc, 1, 4); sqc += __shfl_xor(sqc, 2, 4);

        const float na = sqrtf(sqa);
        const float nc = sqrtf(sqc);
        const float sa = (na > MAXN) ? MAXN / (na + 1e-7f) : 1.f;
        const float sc = (nc > MAXN) ? MAXN / (nc + 1e-7f) : 1.f;

        const float dot = a.x * c.x + a.y * c.y + a.z * c.z + a.w * c.w;
        acc += dot * (sa * sc);
    }

    // linear parts folded into the same reduction
    if (t < NF) {
        acc += w_sparse[s_idx[t]];
    } else if (t >= 64 && t < 64 + LIN) {
        acc += dense[b * LIN + (t - 64)] * w_dense[t - 64];
    }

    // block-wide reduction: wave shuffle + LDS across 4 waves
    for (int m = 1; m < 64; m <<= 1) acc += __shfl_xor(acc, m, 64);
    if ((t & 63) == 0) s_wsum[t >> 6] = acc;
    __syncthreads();
    if (t == 0) {
        const float x = s_wsum[0] + s_wsum[1] + s_wsum[2] + s_wsum[3] + b_dense[0];
        out[b] = 1.f / (1.f + expf(-x));
    }
}

extern "C" void kernel_launch(void* const* d_in, const int* in_sizes, int n_in,
                              void* d_out, int out_size, void* d_ws, size_t ws_size,
                              hipStream_t stream) {
    const float* dense    = (const float*)d_in[0];
    const int*   sparse   = (const int*)d_in[1];
    const float* tables   = (const float*)d_in[2];
    const float* w_sparse = (const float*)d_in[3];
    const float* w_dense  = (const float*)d_in[4];
    const float* b_dense  = (const float*)d_in[5];
    float* out = (float*)d_out;

    const int B = in_sizes[0] / LIN;  // 4096
    ffm_kernel<<<B, 256, 0, stream>>>(dense, sparse, tables, w_sparse,
                                      w_dense, b_dense, out);
}

// Round 2
// 61.754 us; speedup vs baseline: 1.0035x; 1.0035x over previous
//
#include <hip/hip_runtime.h>
#include <math.h>

#define NF 26
#define PF 40000
#define D 16
#define VD (NF * PF * D)   // elements per field table = 16,640,000
#define LIN 13
#define NPAIRS 325         // 26*25/2
#define MAXN 0.01f
#define ITERS 6            // ceil(325/64)

__global__ __launch_bounds__(256) void ffm_kernel(
    const float* __restrict__ dense,     // [B, LIN]
    const int*   __restrict__ sparse,    // [B, NF]
    const float* __restrict__ tables,    // [NF, V, D]
    const float* __restrict__ w_sparse,  // [V]
    const float* __restrict__ w_dense,   // [LIN]
    const float* __restrict__ b_dense,   // [1]
    float* __restrict__ out)             // [B]
{
    const int b = blockIdx.x;
    const int t = threadIdx.x;

    __shared__ int   s_idx[NF];
    __shared__ float s_wsum[4];

    if (t < NF) s_idx[t] = sparse[b * NF + t] + t * PF;
    __syncthreads();

    // ---- early-issue the small gathers so their latency hides under the loop
    const float bd = b_dense[0];
    float lin = 0.f;
    if (t < NF) {
        lin = w_sparse[s_idx[t]];
    } else if (t >= 64 && t < 64 + LIN) {
        lin = dense[b * LIN + (t - 64)] * w_dense[t - 64];
    }

    const int g4 = t >> 2;   // pair-group id within block, 0..63
    const int l4 = t & 3;    // lane within group

    // ---- phase 1: decode ALL pairs, issue ALL loads (12 outstanding/thread)
    float4 va[ITERS], vc[ITERS];
    float  vmask[ITERS];
    #pragma unroll
    for (int it = 0; it < ITERS; ++it) {
        const int praw = g4 + it * 64;
        const int p = (praw < NPAIRS) ? praw : (NPAIRS - 1);
        vmask[it] = (praw < NPAIRS) ? 1.f : 0.f;

        // i = floor((51 - sqrt(51^2 - 8p))/2), with integer fixup
        int i = (int)((51.0f - sqrtf(2601.0f - 8.0f * (float)p)) * 0.5f);
        while ((((i + 1) * (51 - (i + 1))) >> 1) <= p) ++i;
        while (((i * (51 - i)) >> 1) > p) --i;
        const int j = i + 1 + p - ((i * (51 - i)) >> 1);

        const int ra = s_idx[j];  // row in table i
        const int rb = s_idx[i];  // row in table j

        va[it] = *reinterpret_cast<const float4*>(
            tables + (size_t)i * VD + (size_t)ra * D + 4 * l4);
        vc[it] = *reinterpret_cast<const float4*>(
            tables + (size_t)j * VD + (size_t)rb * D + 4 * l4);
    }

    // ---- phase 2: norms (4-lane shfl reduce), renorm scales, dots
    float acc = 0.f;
    #pragma unroll
    for (int it = 0; it < ITERS; ++it) {
        const float4 a = va[it];
        const float4 c = vc[it];

        float sqa = a.x * a.x + a.y * a.y + a.z * a.z + a.w * a.w;
        float sqc = c.x * c.x + c.y * c.y + c.z * c.z + c.w * c.w;
        sqa += __shfl_xor(sqa, 1, 4); sqa += __shfl_xor(sqa, 2, 4);
        sqc += __shfl_xor(sqc, 1, 4); sqc += __shfl_xor(sqc, 2, 4);

        const float na = sqrtf(sqa);
        const float nc = sqrtf(sqc);
        const float sa = (na > MAXN) ? MAXN / (na + 1e-7f) : 1.f;
        const float sc = (nc > MAXN) ? MAXN / (nc + 1e-7f) : 1.f;

        const float dot = a.x * c.x + a.y * c.y + a.z * c.z + a.w * c.w;
        acc += vmask[it] * (dot * sa * sc);
    }

    acc += lin;

    // block-wide reduction: wave shuffle + LDS across 4 waves
    for (int m = 1; m < 64; m <<= 1) acc += __shfl_xor(acc, m, 64);
    if ((t & 63) == 0) s_wsum[t >> 6] = acc;
    __syncthreads();
    if (t == 0) {
        const float x = s_wsum[0] + s_wsum[1] + s_wsum[2] + s_wsum[3] + bd;
        out[b] = 1.f / (1.f + expf(-x));
    }
}

extern "C" void kernel_launch(void* const* d_in, const int* in_sizes, int n_in,
                              void* d_out, int out_size, void* d_ws, size_t ws_size,
                              hipStream_t stream) {
    const float* dense    = (const float*)d_in[0];
    const int*   sparse   = (const int*)d_in[1];
    const float* tables   = (const float*)d_in[2];
    const float* w_sparse = (const float*)d_in[3];
    const float* w_dense  = (const float*)d_in[4];
    const float* b_dense  = (const float*)d_in[5];
    float* out = (float*)d_out;

    const int B = in_sizes[0] / LIN;  // 4096
    ffm_kernel<<<B, 256, 0, stream>>>(dense, sparse, tables, w_sparse,
                                      w_dense, b_dense, out);
}